// Round 3
// baseline (277.096 us; speedup 1.0000x reference)
//
#include <hip/hip_runtime.h>

#define SEQ 4096
#define DM 1024
#define NH 16
#define DK 64

typedef _Float16 half8 __attribute__((ext_vector_type(8)));
typedef _Float16 half4v __attribute__((ext_vector_type(4)));
typedef float f32x4 __attribute__((ext_vector_type(4)));

#define MFMA16(a, b, c) __builtin_amdgcn_mfma_f32_16x16x32_f16((a), (b), (c), 0, 0, 0)
#define GLOAD_LDS(g, l)                                                                  \
    __builtin_amdgcn_global_load_lds((const __attribute__((address_space(1))) void*)(g), \
                                     (__attribute__((address_space(3))) void*)(l), 16, 0, 0)

// all-16-lane max via DPP (VALU pipe, ~5cyc/step) -- replaces 4-deep ds_bpermute chain
__device__ __forceinline__ float dpp_max16(float x) {
    x = fmaxf(x, __int_as_float(__builtin_amdgcn_update_dpp(
                     0, __float_as_int(x), 0xB1, 0xF, 0xF, true)));  // quad_perm xor1
    x = fmaxf(x, __int_as_float(__builtin_amdgcn_update_dpp(
                     0, __float_as_int(x), 0x4E, 0xF, 0xF, true)));  // quad_perm xor2
    x = fmaxf(x, __int_as_float(__builtin_amdgcn_update_dpp(
                     0, __float_as_int(x), 0x124, 0xF, 0xF, true)));  // row_ror:4
    x = fmaxf(x, __int_as_float(__builtin_amdgcn_update_dpp(
                     0, __float_as_int(x), 0x128, 0xF, 0xF, true)));  // row_ror:8
    return x;
}

// ---------------- fp32 -> fp16 conversion (7 tensors in one launch, 16B stores) --------
__global__ void cvt_all(const float* __restrict__ q, const float* __restrict__ k,
                        const float* __restrict__ v, const float* __restrict__ wq,
                        const float* __restrict__ wk, const float* __restrict__ wv,
                        const float* __restrict__ wo, _Float16* __restrict__ qh,
                        _Float16* __restrict__ kh, _Float16* __restrict__ vh,
                        _Float16* __restrict__ wqh, _Float16* __restrict__ wkh,
                        _Float16* __restrict__ wvh, _Float16* __restrict__ woh) {
    int z = blockIdx.y;
    const float* src;
    _Float16* dst;
    int n;
    switch (z) {
    case 0: src = q;  dst = qh;  n = SEQ * DM; break;
    case 1: src = k;  dst = kh;  n = SEQ * DM; break;
    case 2: src = v;  dst = vh;  n = SEQ * DM; break;
    case 3: src = wq; dst = wqh; n = DM * DM;  break;
    case 4: src = wk; dst = wkh; n = DM * DM;  break;
    case 5: src = wv; dst = wvh; n = DM * DM;  break;
    default: src = wo; dst = woh; n = DM * DM; break;
    }
    int idx = (blockIdx.x * 256 + threadIdx.x) * 8;
    if (idx >= n) return;
    float4 f0 = *(const float4*)(src + idx);
    float4 f1 = *(const float4*)(src + idx + 4);
    half8 h;
    h[0] = (_Float16)f0.x; h[1] = (_Float16)f0.y; h[2] = (_Float16)f0.z; h[3] = (_Float16)f0.w;
    h[4] = (_Float16)f1.x; h[5] = (_Float16)f1.y; h[6] = (_Float16)f1.z; h[7] = (_Float16)f1.w;
    *(half8*)(dst + idx) = h;
}

// ---------------- m97-structure f16 GEMM, BK=64 (R6 body, best measured) ----------------
template <int MT>  // M-tile: 128 (qkv) or 64 (out); N-tile fixed 128
__device__ __forceinline__ void gemm_bk64(const _Float16* __restrict__ A,
                                          const _Float16* __restrict__ B, int m0, int n0,
                                          _Float16* As, _Float16* Bs, f32x4 (*acc)[4]) {
    constexpr int MI = MT / 32;
    constexpr int ACH = MT / 64;
    const int tid = threadIdx.x;
    const int wave = tid >> 6, lane = tid & 63;
    const int quad = lane >> 4, l16 = lane & 15;
    const int wr = (wave >> 1) * (MT / 2);
    const int wc = (wave & 1) * 64;
    const int srow = tid >> 2, scol = (tid & 3) * 8;

    for (int k0 = 0; k0 < DM; k0 += 64) {
#pragma unroll
        for (int p = 0; p < 2; ++p) {
            int kc = k0 + p * 32 + scol;
#pragma unroll
            for (int j = 0; j < ACH; ++j)
                GLOAD_LDS(A + (size_t)(m0 + j * 64 + srow) * DM + kc,
                          As + p * (MT * 32) + j * 2048 + tid * 8);
#pragma unroll
            for (int j = 0; j < 2; ++j)
                GLOAD_LDS(B + (size_t)(n0 + j * 64 + srow) * DM + kc,
                          Bs + p * 4096 + j * 2048 + tid * 8);
        }
        __syncthreads();
#pragma unroll
        for (int p = 0; p < 2; ++p) {
            half8 af[MI], bf[4];
#pragma unroll
            for (int mi = 0; mi < MI; ++mi)
                af[mi] = *(const half8*)&As[p * (MT * 32) + (wr + mi * 16 + l16) * 32 + quad * 8];
#pragma unroll
            for (int ni = 0; ni < 4; ++ni)
                bf[ni] = *(const half8*)&Bs[p * 4096 + (wc + ni * 16 + l16) * 32 + quad * 8];
#pragma unroll
            for (int mi = 0; mi < MI; ++mi)
#pragma unroll
                for (int ni = 0; ni < 4; ++ni)
                    acc[mi][ni] = MFMA16(af[mi], bf[ni], acc[mi][ni]);
        }
        __syncthreads();
    }
}

// ---------------- QKV projections: 128x128 tiles, grid (32,8,3) = 3 blocks/CU ----------
__global__ void __launch_bounds__(256, 3) gemm_qkv(
    const _Float16* __restrict__ qh, const _Float16* __restrict__ kh,
    const _Float16* __restrict__ vh, const _Float16* __restrict__ wqh,
    const _Float16* __restrict__ wkh, const _Float16* __restrict__ wvh,
    const float* __restrict__ bq, const float* __restrict__ bk, const float* __restrict__ bv,
    _Float16* __restrict__ Qo, _Float16* __restrict__ Ko, _Float16* __restrict__ Vt) {
    __shared__ _Float16 As[2 * 128 * 32];
    __shared__ _Float16 Bs[2 * 128 * 32];
    int z = blockIdx.z;
    const _Float16 *A, *B;
    const float* bias;
    float scale;
    if (z == 0) { A = qh; B = wqh; bias = bq; scale = 0.125f; }  // 1/sqrt(64)
    else if (z == 1) { A = kh; B = wkh; bias = bk; scale = 1.0f; }
    else { A = vh; B = wvh; bias = bv; scale = 1.0f; }

    int m0 = blockIdx.x * 128;
    int n0 = blockIdx.y * 128;
    f32x4 acc[4][4] = {};
    gemm_bk64<128>(A, B, m0, n0, As, Bs, acc);

    const int tid = threadIdx.x;
    const int wave = tid >> 6, lane = tid & 63;
    const int quad = lane >> 4, l16 = lane & 15;
    const int wr = (wave >> 1) * 64;
    const int wc = (wave & 1) * 64;
    float bs[4];
#pragma unroll
    for (int ni = 0; ni < 4; ++ni) bs[ni] = bias[n0 + wc + ni * 16 + l16];

    if (z < 2) {
        _Float16* C = (z == 0) ? Qo : Ko;
#pragma unroll
        for (int mi = 0; mi < 4; ++mi)
#pragma unroll
            for (int ni = 0; ni < 4; ++ni) {
                int m = m0 + wr + mi * 16 + quad * 4;
                int n = n0 + wc + ni * 16 + l16;
#pragma unroll
                for (int r = 0; r < 4; ++r)
                    C[(size_t)(m + r) * DM + n] = (_Float16)((acc[mi][ni][r] + bs[ni]) * scale);
            }
    } else {
#pragma unroll
        for (int mi = 0; mi < 4; ++mi)
#pragma unroll
            for (int ni = 0; ni < 4; ++ni) {
                int m = m0 + wr + mi * 16 + quad * 4;
                int n = n0 + wc + ni * 16 + l16;
                half4v p;
#pragma unroll
                for (int r = 0; r < 4; ++r) p[r] = (_Float16)(acc[mi][ni][r] + bs[ni]);
                *(half4v*)(Vt + (size_t)n * SEQ + m) = p;  // m % 4 == 0 -> 8B aligned
            }
    }
}

// ---------------- output projection: 64x128 tiles, grid (64,8) = 2 blocks/CU ----------
__global__ void __launch_bounds__(256, 3) gemm_out(const _Float16* __restrict__ Xh,
                                                   const _Float16* __restrict__ woh,
                                                   const float* __restrict__ bo,
                                                   float* __restrict__ out) {
    __shared__ _Float16 As[2 * 64 * 32];
    __shared__ _Float16 Bs[2 * 128 * 32];
    int m0 = blockIdx.x * 64;
    int n0 = blockIdx.y * 128;
    f32x4 acc[2][4] = {};
    gemm_bk64<64>(Xh, woh, m0, n0, As, Bs, acc);

    const int tid = threadIdx.x;
    const int wave = tid >> 6, lane = tid & 63;
    const int quad = lane >> 4, l16 = lane & 15;
    const int wr = (wave >> 1) * 32;
    const int wc = (wave & 1) * 64;
#pragma unroll
    for (int mi = 0; mi < 2; ++mi)
#pragma unroll
        for (int ni = 0; ni < 4; ++ni) {
            int m = m0 + wr + mi * 16 + quad * 4;
            int n = n0 + wc + ni * 16 + l16;
            float b = bo[n];
#pragma unroll
            for (int r = 0; r < 4; ++r) out[(size_t)(m + r) * DM + n] = acc[mi][ni][r] + b;
        }
}

// ---------------- windowed attention: 8 queries/wave, 2x occupancy -------------------
// R2 post-mortem: ILP changes were neutral -> the stall is not load latency on the
// direct path; VALUBusy 26% == 4 waves/SIMD x ~6.5% per-wave issue, i.e. all resident
// waves stall simultaneously and there is nothing to interleave. Wave count was pinned
// at 4096 (= 4/SIMD) by the 16-queries-per-wave mapping.
// Fix: 8 queries per wave -- MFMA tile rows 8..15 DUPLICATE rows 0..7 (Q loaded with
// l16&7; only quad<2 stores). Grid doubles to 2048 blocks = 8 blocks/CU = 8 waves/SIMD.
// MFMA FLOPs double, but MfmaUtil was 4.7% -- we spend idle matrix-pipe slots to buy
// 2x latency hiding. Body is the exact R0 inner loop (measured 48 VGPR), safely under
// the 64-VGPR cap implied by __launch_bounds__(256,8) -- no R1-style spill.
__global__ void __launch_bounds__(256, 8) attn_kernel(const _Float16* __restrict__ Q,
                                                      const _Float16* __restrict__ K,
                                                      const _Float16* __restrict__ Vt,
                                                      _Float16* __restrict__ X) {
    __shared__ _Float16 Pl[4][16][32];
    int tid = threadIdx.x;
    int wave = tid >> 6, lane = tid & 63;
    int quad = lane >> 4, l16 = lane & 15;
    int h = blockIdx.y;
    int bx = ((blockIdx.x & 7) << 4) + (blockIdx.x >> 3);  // 128 blocks -> 8 XCD chunks of 16
    int q0 = bx * 32 + wave * 8;

    const _Float16* Qp = Q + (size_t)(q0 + (l16 & 7)) * DM + h * DK + quad * 8;
    half8 aq0 = *(const half8*)(Qp);
    half8 aq1 = *(const half8*)(Qp + 32);
    const half8 ones = {(_Float16)1, (_Float16)1, (_Float16)1, (_Float16)1,
                        (_Float16)1, (_Float16)1, (_Float16)1, (_Float16)1};

    float rowM[4], rowL[4];
    f32x4 o[4] = {};
#pragma unroll
    for (int r = 0; r < 4; ++r) { rowM[r] = -__builtin_inff(); rowL[r] = 0.f; }

    int kstart = (q0 > 127) ? ((q0 - 127) & ~31) : 0;
    int kend = q0 + 135;  // max row q0+7, window right edge +128
    if (kend > SEQ - 1) kend = SEQ - 1;

    for (int kt = kstart; kt <= kend; kt += 32) {
        f32x4 s[2];
#pragma unroll
        for (int cf = 0; cf < 2; ++cf) {
            int krow = kt + cf * 16 + l16;  // < SEQ structurally (32-aligned, SEQ%32==0)
            const _Float16* Kp = K + (size_t)krow * DM + h * DK + quad * 8;
            half8 b0 = *(const half8*)(Kp);
            half8 b1 = *(const half8*)(Kp + 32);
            f32x4 z = {};
            z = MFMA16(aq0, b0, z);
            z = MFMA16(aq1, b1, z);
            s[cf] = z;
        }
        // wave-uniform: tile fully inside every (real) row's window?
        const bool full = (kt >= q0 - 120) && (kt <= q0 + 97);
        float alpha[4];
#pragma unroll
        for (int r = 0; r < 4; ++r) {
            float x0 = s[0][r], x1 = s[1][r];
            if (!full) {
                int row = q0 + ((quad * 4 + r) & 7);  // rows 8..15 duplicate 0..7
                int key0 = kt + l16, key1 = kt + 16 + l16;
                if (key0 < row - 127 || key0 > row + 128) x0 = -1e30f;
                if (key1 < row - 127 || key1 > row + 128) x1 = -1e30f;
            }
            float t = dpp_max16(fmaxf(x0, x1));
            float mnew = fmaxf(rowM[r], t);
            alpha[r] = __expf(rowM[r] - mnew);  // first tile: exp(-inf - finite) = 0
            float p0 = __expf(x0 - mnew);
            float p1 = __expf(x1 - mnew);
            Pl[wave][quad * 4 + r][l16] = (_Float16)p0;
            Pl[wave][quad * 4 + r][l16 + 16] = (_Float16)p1;
            rowM[r] = mnew;
        }
        // P: C-layout -> A-operand layout via per-wave LDS round-trip (wave-internal)
        half8 ap = *(const half8*)&Pl[wave][l16][quad * 8];
        f32x4 ts = {};
        ts = MFMA16(ap, ones, ts);  // ts[r] = this tile's row sum (all cols identical)
#pragma unroll
        for (int r = 0; r < 4; ++r) rowL[r] = rowL[r] * alpha[r] + ts[r];
#pragma unroll
        for (int ni = 0; ni < 4; ++ni) {
#pragma unroll
            for (int r = 0; r < 4; ++r) o[ni][r] *= alpha[r];
            const _Float16* Vp = Vt + (size_t)(h * DK + ni * 16 + l16) * SEQ + kt + quad * 8;
            half8 bv = *(const half8*)(Vp);
            o[ni] = MFMA16(ap, bv, o[ni]);
        }
    }

    if (quad < 2) {  // rows 0..7 are the real queries
        float rinv[4];
#pragma unroll
        for (int r = 0; r < 4; ++r) rinv[r] = 1.0f / rowL[r];
#pragma unroll
        for (int ni = 0; ni < 4; ++ni) {
            int n = h * DK + ni * 16 + l16;
#pragma unroll
            for (int r = 0; r < 4; ++r) {
                int m = q0 + quad * 4 + r;
                X[(size_t)m * DM + n] = (_Float16)(o[ni][r] * rinv[r]);
            }
        }
    }
}

extern "C" void kernel_launch(void* const* d_in, const int* in_sizes, int n_in, void* d_out,
                              int out_size, void* d_ws, size_t ws_size, hipStream_t stream) {
    const float* q  = (const float*)d_in[0];
    const float* k  = (const float*)d_in[1];
    const float* v  = (const float*)d_in[2];
    const float* wq = (const float*)d_in[3];
    const float* bq = (const float*)d_in[4];
    const float* wk = (const float*)d_in[5];
    const float* bk = (const float*)d_in[6];
    const float* wv = (const float*)d_in[7];
    const float* bv = (const float*)d_in[8];
    const float* wo = (const float*)d_in[9];
    const float* bo = (const float*)d_in[10];

    const size_t SZ_T = (size_t)SEQ * DM * sizeof(_Float16);  // 8 MB
    const size_t SZ_W = (size_t)DM * DM * sizeof(_Float16);   // 2 MB
    char* p = (char*)d_ws;
    _Float16* qh  = (_Float16*)(p);
    _Float16* kh  = (_Float16*)(p + SZ_T);
    _Float16* vh  = (_Float16*)(p + 2 * SZ_T);
    _Float16* wqh = (_Float16*)(p + 3 * SZ_T);
    _Float16* wkh = (_Float16*)(p + 3 * SZ_T + SZ_W);
    _Float16* wvh = (_Float16*)(p + 3 * SZ_T + 2 * SZ_W);
    _Float16* woh = (_Float16*)(p + 3 * SZ_T + 3 * SZ_W);
    _Float16* Qo  = (_Float16*)(p + 3 * SZ_T + 4 * SZ_W);
    _Float16* Ko  = (_Float16*)(p + 4 * SZ_T + 4 * SZ_W);
    _Float16* Vt  = (_Float16*)(p + 5 * SZ_T + 4 * SZ_W);
    _Float16* Xh  = qh;  // alias: qh dead after gemm_qkv (stream-serialized)

    cvt_all<<<dim3(2048, 7), 256, 0, stream>>>(q, k, v, wq, wk, wv, wo, qh, kh, vh, wqh, wkh,
                                               wvh, woh);
    gemm_qkv<<<dim3(32, 8, 3), 256, 0, stream>>>(qh, kh, vh, wqh, wkh, wvh, bq, bk, bv, Qo, Ko,
                                                 Vt);
    attn_kernel<<<dim3(SEQ / 32, NH), 256, 0, stream>>>(Qo, Ko, Vt, Xh);
    gemm_out<<<dim3(64, 8), 256, 0, stream>>>(Xh, woh, bo, (float*)d_out);
}

// Round 4
// 193.359 us; speedup vs baseline: 1.4331x; 1.4331x over previous
//
#include <hip/hip_runtime.h>

#define SEQ 4096
#define DM 1024
#define NH 16
#define DK 64

typedef _Float16 half8 __attribute__((ext_vector_type(8)));
typedef _Float16 half4v __attribute__((ext_vector_type(4)));
typedef float f32x4 __attribute__((ext_vector_type(4)));

#define MFMA16(a, b, c) __builtin_amdgcn_mfma_f32_16x16x32_f16((a), (b), (c), 0, 0, 0)
#define GLOAD_LDS(g, l)                                                                  \
    __builtin_amdgcn_global_load_lds((const __attribute__((address_space(1))) void*)(g), \
                                     (__attribute__((address_space(3))) void*)(l), 16, 0, 0)

// all-16-lane max via DPP (VALU pipe, ~5cyc/step) -- replaces 4-deep ds_bpermute chain
__device__ __forceinline__ float dpp_max16(float x) {
    x = fmaxf(x, __int_as_float(__builtin_amdgcn_update_dpp(
                     0, __float_as_int(x), 0xB1, 0xF, 0xF, true)));  // quad_perm xor1
    x = fmaxf(x, __int_as_float(__builtin_amdgcn_update_dpp(
                     0, __float_as_int(x), 0x4E, 0xF, 0xF, true)));  // quad_perm xor2
    x = fmaxf(x, __int_as_float(__builtin_amdgcn_update_dpp(
                     0, __float_as_int(x), 0x124, 0xF, 0xF, true)));  // row_ror:4
    x = fmaxf(x, __int_as_float(__builtin_amdgcn_update_dpp(
                     0, __float_as_int(x), 0x128, 0xF, 0xF, true)));  // row_ror:8
    return x;
}

// ---------------- fp32 -> fp16 conversion (7 tensors in one launch, 16B stores) --------
__global__ void cvt_all(const float* __restrict__ q, const float* __restrict__ k,
                        const float* __restrict__ v, const float* __restrict__ wq,
                        const float* __restrict__ wk, const float* __restrict__ wv,
                        const float* __restrict__ wo, _Float16* __restrict__ qh,
                        _Float16* __restrict__ kh, _Float16* __restrict__ vh,
                        _Float16* __restrict__ wqh, _Float16* __restrict__ wkh,
                        _Float16* __restrict__ wvh, _Float16* __restrict__ woh) {
    int z = blockIdx.y;
    const float* src;
    _Float16* dst;
    int n;
    switch (z) {
    case 0: src = q;  dst = qh;  n = SEQ * DM; break;
    case 1: src = k;  dst = kh;  n = SEQ * DM; break;
    case 2: src = v;  dst = vh;  n = SEQ * DM; break;
    case 3: src = wq; dst = wqh; n = DM * DM;  break;
    case 4: src = wk; dst = wkh; n = DM * DM;  break;
    case 5: src = wv; dst = wvh; n = DM * DM;  break;
    default: src = wo; dst = woh; n = DM * DM; break;
    }
    int idx = (blockIdx.x * 256 + threadIdx.x) * 8;
    if (idx >= n) return;
    float4 f0 = *(const float4*)(src + idx);
    float4 f1 = *(const float4*)(src + idx + 4);
    half8 h;
    h[0] = (_Float16)f0.x; h[1] = (_Float16)f0.y; h[2] = (_Float16)f0.z; h[3] = (_Float16)f0.w;
    h[4] = (_Float16)f1.x; h[5] = (_Float16)f1.y; h[6] = (_Float16)f1.z; h[7] = (_Float16)f1.w;
    *(half8*)(dst + idx) = h;
}

// ---------------- m97-structure f16 GEMM, BK=64 (R6 body, best measured) ----------------
template <int MT>  // M-tile: 128 (qkv) or 64 (out); N-tile fixed 128
__device__ __forceinline__ void gemm_bk64(const _Float16* __restrict__ A,
                                          const _Float16* __restrict__ B, int m0, int n0,
                                          _Float16* As, _Float16* Bs, f32x4 (*acc)[4]) {
    constexpr int MI = MT / 32;
    constexpr int ACH = MT / 64;
    const int tid = threadIdx.x;
    const int wave = tid >> 6, lane = tid & 63;
    const int quad = lane >> 4, l16 = lane & 15;
    const int wr = (wave >> 1) * (MT / 2);
    const int wc = (wave & 1) * 64;
    const int srow = tid >> 2, scol = (tid & 3) * 8;

    for (int k0 = 0; k0 < DM; k0 += 64) {
#pragma unroll
        for (int p = 0; p < 2; ++p) {
            int kc = k0 + p * 32 + scol;
#pragma unroll
            for (int j = 0; j < ACH; ++j)
                GLOAD_LDS(A + (size_t)(m0 + j * 64 + srow) * DM + kc,
                          As + p * (MT * 32) + j * 2048 + tid * 8);
#pragma unroll
            for (int j = 0; j < 2; ++j)
                GLOAD_LDS(B + (size_t)(n0 + j * 64 + srow) * DM + kc,
                          Bs + p * 4096 + j * 2048 + tid * 8);
        }
        __syncthreads();
#pragma unroll
        for (int p = 0; p < 2; ++p) {
            half8 af[MI], bf[4];
#pragma unroll
            for (int mi = 0; mi < MI; ++mi)
                af[mi] = *(const half8*)&As[p * (MT * 32) + (wr + mi * 16 + l16) * 32 + quad * 8];
#pragma unroll
            for (int ni = 0; ni < 4; ++ni)
                bf[ni] = *(const half8*)&Bs[p * 4096 + (wc + ni * 16 + l16) * 32 + quad * 8];
#pragma unroll
            for (int mi = 0; mi < MI; ++mi)
#pragma unroll
                for (int ni = 0; ni < 4; ++ni)
                    acc[mi][ni] = MFMA16(af[mi], bf[ni], acc[mi][ni]);
        }
        __syncthreads();
    }
}

// ---------------- QKV projections: 128x128 tiles, grid (32,8,3) = 3 blocks/CU ----------
__global__ void __launch_bounds__(256, 3) gemm_qkv(
    const _Float16* __restrict__ qh, const _Float16* __restrict__ kh,
    const _Float16* __restrict__ vh, const _Float16* __restrict__ wqh,
    const _Float16* __restrict__ wkh, const _Float16* __restrict__ wvh,
    const float* __restrict__ bq, const float* __restrict__ bk, const float* __restrict__ bv,
    _Float16* __restrict__ Qo, _Float16* __restrict__ Ko, _Float16* __restrict__ Vt) {
    __shared__ _Float16 As[2 * 128 * 32];
    __shared__ _Float16 Bs[2 * 128 * 32];
    int z = blockIdx.z;
    const _Float16 *A, *B;
    const float* bias;
    float scale;
    if (z == 0) { A = qh; B = wqh; bias = bq; scale = 0.125f; }  // 1/sqrt(64)
    else if (z == 1) { A = kh; B = wkh; bias = bk; scale = 1.0f; }
    else { A = vh; B = wvh; bias = bv; scale = 1.0f; }

    int m0 = blockIdx.x * 128;
    int n0 = blockIdx.y * 128;
    f32x4 acc[4][4] = {};
    gemm_bk64<128>(A, B, m0, n0, As, Bs, acc);

    const int tid = threadIdx.x;
    const int wave = tid >> 6, lane = tid & 63;
    const int quad = lane >> 4, l16 = lane & 15;
    const int wr = (wave >> 1) * 64;
    const int wc = (wave & 1) * 64;
    float bs[4];
#pragma unroll
    for (int ni = 0; ni < 4; ++ni) bs[ni] = bias[n0 + wc + ni * 16 + l16];

    if (z < 2) {
        _Float16* C = (z == 0) ? Qo : Ko;
#pragma unroll
        for (int mi = 0; mi < 4; ++mi)
#pragma unroll
            for (int ni = 0; ni < 4; ++ni) {
                int m = m0 + wr + mi * 16 + quad * 4;
                int n = n0 + wc + ni * 16 + l16;
#pragma unroll
                for (int r = 0; r < 4; ++r)
                    C[(size_t)(m + r) * DM + n] = (_Float16)((acc[mi][ni][r] + bs[ni]) * scale);
            }
    } else {
#pragma unroll
        for (int mi = 0; mi < 4; ++mi)
#pragma unroll
            for (int ni = 0; ni < 4; ++ni) {
                int m = m0 + wr + mi * 16 + quad * 4;
                int n = n0 + wc + ni * 16 + l16;
                half4v p;
#pragma unroll
                for (int r = 0; r < 4; ++r) p[r] = (_Float16)(acc[mi][ni][r] + bs[ni]);
                *(half4v*)(Vt + (size_t)n * SEQ + m) = p;  // m % 4 == 0 -> 8B aligned
            }
    }
}

// ---------------- output projection: 64x128 tiles, grid (64,8) = 2 blocks/CU ----------
__global__ void __launch_bounds__(256, 3) gemm_out(const _Float16* __restrict__ Xh,
                                                   const _Float16* __restrict__ woh,
                                                   const float* __restrict__ bo,
                                                   float* __restrict__ out) {
    __shared__ _Float16 As[2 * 64 * 32];
    __shared__ _Float16 Bs[2 * 128 * 32];
    int m0 = blockIdx.x * 64;
    int n0 = blockIdx.y * 128;
    f32x4 acc[2][4] = {};
    gemm_bk64<64>(Xh, woh, m0, n0, As, Bs, acc);

    const int tid = threadIdx.x;
    const int wave = tid >> 6, lane = tid & 63;
    const int quad = lane >> 4, l16 = lane & 15;
    const int wr = (wave >> 1) * 32;
    const int wc = (wave & 1) * 64;
#pragma unroll
    for (int mi = 0; mi < 2; ++mi)
#pragma unroll
        for (int ni = 0; ni < 4; ++ni) {
            int m = m0 + wr + mi * 16 + quad * 4;
            int n = n0 + wc + ni * 16 + l16;
            float b = bo[n];
#pragma unroll
            for (int r = 0; r < 4; ++r) out[(size_t)(m + r) * DM + n] = acc[mi][ni][r] + b;
        }
}

// ---------------- windowed attention: R0 body + bulk LDS K-staging --------------------
// R1/R3 post-mortem: 8 waves/SIMD forces <=64-VGPR cap -> spills (+170..250MB scratch
// traffic). Occupancy is NOT the lever. R0's real stall: 48-VGPR allocation leaves no
// registers for in-flight loads, so the 8 global K/V loads per tile serialize at
// ~300-900cyc each (~10k cyc/tile). Plain-load "prefetch" (R2) was neutral -- the
// scheduler sinks loads to uses. Fix: pay ALL K latency once via bulk global_load_lds:
//   - per 64-query block, stage K rows [q0b-128, q0b+192) x 64 dims (40KB) up front,
//     10 gload_lds/thread issued back-to-back, one barrier.
//   - T2/T21 swizzle: linear LDS dest, XOR-pre-swizzled global source (unit ^= row&7),
//     same XOR on the ds_read_b128 -> structural-minimum 8-cycle b128, no conflicts.
//   - V stays global, loaded at loop top (used ~700cyc later at PV -> in-tile hiding).
//   - Pl row stride 32->40 halves: de-conflicts the ap b128 read.
// LDS 45KB -> 3 blocks/CU (12 waves/CU). launch_bounds(256,4): 128-VGPR cap, no spill.
__global__ void __launch_bounds__(256, 4) attn_kernel(const _Float16* __restrict__ Q,
                                                      const _Float16* __restrict__ K,
                                                      const _Float16* __restrict__ Vt,
                                                      _Float16* __restrict__ X) {
    __shared__ _Float16 Ks[320 * 64];   // 40KB, unit-swizzled (16B unit ^= row&7)
    __shared__ _Float16 Pl[4][16][40];  // 5KB, padded stride
    int tid = threadIdx.x;
    int wave = tid >> 6, lane = tid & 63;
    int quad = lane >> 4, l16 = lane & 15;
    int h = blockIdx.y;
    int bx = ((blockIdx.x & 7) << 3) + (blockIdx.x >> 3);  // XCD-contiguous q-spans
    int q0b = bx * 64;
    int q0 = q0b + wave * 16;
    int kspan0 = q0b - 128;

    // ---- bulk K staging: 320 rows x 8 units(16B) = 2560 units, 10 per thread --------
    const _Float16* Kg = K + h * DK;
#pragma unroll
    for (int i = 0; i < 10; ++i) {
        int U = i * 256 + tid;        // linear 16B-unit index in LDS
        int row = U >> 3, u = U & 7;  // rel row, unit-in-row
        int rg = kspan0 + row;
        rg = rg < 0 ? 0 : (rg > SEQ - 1 ? SEQ - 1 : rg);  // clamp: garbage rows are
                                                          // always window-masked
        GLOAD_LDS(Kg + (size_t)rg * DM + ((u ^ (row & 7)) << 3), Ks + U * 8);
    }

    const _Float16* Qp = Q + (size_t)(q0 + l16) * DM + h * DK + quad * 8;
    half8 aq0 = *(const half8*)(Qp);
    half8 aq1 = *(const half8*)(Qp + 32);
    const half8 ones = {(_Float16)1, (_Float16)1, (_Float16)1, (_Float16)1,
                        (_Float16)1, (_Float16)1, (_Float16)1, (_Float16)1};

    float rowM[4], rowL[4];
    f32x4 o[4] = {};
#pragma unroll
    for (int r = 0; r < 4; ++r) { rowM[r] = -__builtin_inff(); rowL[r] = 0.f; }

    int kstart = (q0 > 127) ? ((q0 - 127) & ~31) : 0;
    int kend = q0 + 143;
    if (kend > SEQ - 1) kend = SEQ - 1;
    const int xk = l16 & 7;

    __syncthreads();  // staging complete (barrier drains vmcnt)

    for (int kt = kstart; kt <= kend; kt += 32) {
        int rel = kt - kspan0;  // in [0, 320), multiple of 32
        // V loads for this tile -- consumed at the PV MFMAs ~700cyc later
        half8 vb[4];
#pragma unroll
        for (int ni = 0; ni < 4; ++ni)
            vb[ni] = *(const half8*)(Vt + (size_t)(h * DK + ni * 16 + l16) * SEQ + kt + quad * 8);

        // QK^T from LDS K (swizzled read: row&7 == l16&7 since rel%32==0)
        f32x4 s[2];
#pragma unroll
        for (int cf = 0; cf < 2; ++cf) {
            int rr = rel + cf * 16 + l16;
            half8 b0 = *(const half8*)&Ks[rr * 64 + ((quad ^ xk) << 3)];
            half8 b1 = *(const half8*)&Ks[rr * 64 + (((quad + 4) ^ xk) << 3)];
            f32x4 z = {};
            z = MFMA16(aq0, b0, z);
            z = MFMA16(aq1, b1, z);
            s[cf] = z;
        }
        // wave-uniform: tile fully inside every row's window?
        const bool full = (kt >= q0 - 112) && (kt <= q0 + 97);
        float alpha[4];
#pragma unroll
        for (int r = 0; r < 4; ++r) {
            float x0 = s[0][r], x1 = s[1][r];
            if (!full) {
                int row = q0 + quad * 4 + r;
                int key0 = kt + l16, key1 = kt + 16 + l16;
                if (key0 < row - 127 || key0 > row + 128) x0 = -1e30f;
                if (key1 < row - 127 || key1 > row + 128) x1 = -1e30f;
            }
            float t = dpp_max16(fmaxf(x0, x1));
            float mnew = fmaxf(rowM[r], t);
            alpha[r] = __expf(rowM[r] - mnew);  // first tile: exp(-inf - finite) = 0
            float p0 = __expf(x0 - mnew);
            float p1 = __expf(x1 - mnew);
            Pl[wave][quad * 4 + r][l16] = (_Float16)p0;
            Pl[wave][quad * 4 + r][l16 + 16] = (_Float16)p1;
            rowM[r] = mnew;
        }
        // P: C-layout -> A-operand layout via per-wave LDS round-trip (wave-internal)
        half8 ap = *(const half8*)&Pl[wave][l16][quad * 8];
        f32x4 ts = {};
        ts = MFMA16(ap, ones, ts);  // ts[r] = this tile's row sum (all cols identical)
#pragma unroll
        for (int r = 0; r < 4; ++r) rowL[r] = rowL[r] * alpha[r] + ts[r];
#pragma unroll
        for (int ni = 0; ni < 4; ++ni) {
#pragma unroll
            for (int r = 0; r < 4; ++r) o[ni][r] *= alpha[r];
            o[ni] = MFMA16(ap, vb[ni], o[ni]);
        }
    }

    float rinv[4];
#pragma unroll
    for (int r = 0; r < 4; ++r) rinv[r] = 1.0f / rowL[r];
#pragma unroll
    for (int ni = 0; ni < 4; ++ni) {
        int n = h * DK + ni * 16 + l16;
#pragma unroll
        for (int r = 0; r < 4; ++r) {
            int m = q0 + quad * 4 + r;
            X[(size_t)m * DM + n] = (_Float16)(o[ni][r] * rinv[r]);
        }
    }
}

extern "C" void kernel_launch(void* const* d_in, const int* in_sizes, int n_in, void* d_out,
                              int out_size, void* d_ws, size_t ws_size, hipStream_t stream) {
    const float* q  = (const float*)d_in[0];
    const float* k  = (const float*)d_in[1];
    const float* v  = (const float*)d_in[2];
    const float* wq = (const float*)d_in[3];
    const float* bq = (const float*)d_in[4];
    const float* wk = (const float*)d_in[5];
    const float* bk = (const float*)d_in[6];
    const float* wv = (const float*)d_in[7];
    const float* bv = (const float*)d_in[8];
    const float* wo = (const float*)d_in[9];
    const float* bo = (const float*)d_in[10];

    const size_t SZ_T = (size_t)SEQ * DM * sizeof(_Float16);  // 8 MB
    const size_t SZ_W = (size_t)DM * DM * sizeof(_Float16);   // 2 MB
    char* p = (char*)d_ws;
    _Float16* qh  = (_Float16*)(p);
    _Float16* kh  = (_Float16*)(p + SZ_T);
    _Float16* vh  = (_Float16*)(p + 2 * SZ_T);
    _Float16* wqh = (_Float16*)(p + 3 * SZ_T);
    _Float16* wkh = (_Float16*)(p + 3 * SZ_T + SZ_W);
    _Float16* wvh = (_Float16*)(p + 3 * SZ_T + 2 * SZ_W);
    _Float16* woh = (_Float16*)(p + 3 * SZ_T + 3 * SZ_W);
    _Float16* Qo  = (_Float16*)(p + 3 * SZ_T + 4 * SZ_W);
    _Float16* Ko  = (_Float16*)(p + 4 * SZ_T + 4 * SZ_W);
    _Float16* Vt  = (_Float16*)(p + 5 * SZ_T + 4 * SZ_W);
    _Float16* Xh  = qh;  // alias: qh dead after gemm_qkv (stream-serialized)

    cvt_all<<<dim3(2048, 7), 256, 0, stream>>>(q, k, v, wq, wk, wv, wo, qh, kh, vh, wqh, wkh,
                                               wvh, woh);
    gemm_qkv<<<dim3(32, 8, 3), 256, 0, stream>>>(qh, kh, vh, wqh, wkh, wvh, bq, bk, bv, Qo, Ko,
                                                 Vt);
    attn_kernel<<<dim3(SEQ / 64, NH), 256, 0, stream>>>(Qo, Ko, Vt, Xh);
    gemm_out<<<dim3(64, 8), 256, 0, stream>>>(Xh, woh, bo, (float*)d_out);
}